// Round 4
// baseline (807.976 us; speedup 1.0000x reference)
//
#include <hip/hip_runtime.h>
#include <math.h>

// Problem constants (reference: B,M,N,L,S,KERN = 4,256,256,24,22,256; KERN==M → tile is identity)
constexpr int B_ = 4, M_ = 256, N_ = 256, L_ = 24, S_ = 22;
constexpr int NY = N_ + L_ - 1;   // 279 dispersion-shifted columns
constexpr int YSZ = 280;          // padded Y slice length (one s)

// R3 post-mortem: keeping all 88 a_c[s] per thread in registers never worked —
// allocator left them in scratch (VGPR_Count 88 at a 256 budget) and dur was
// pinned at 733us across three variants (latency-bound scratch reloads).
// Restructure: s is the OUTER loop (in pairs). Per s-pair only 8 normalized
// weights are live; G[l]=H(t,l,s) is computed once and reused by both the
// scatter (phase A) and gather (phase B); Y is two 280-float LDS slices that
// are recycled every iteration (phase B of s only needs Y[:,s]). Every l-loop
// is fully unrolled -> all register arrays statically indexed -> promotable.
__global__ __launch_bounds__(256) __attribute__((amdgpu_waves_per_eu(3, 3)))
void cassi_fused(
    const float* __restrict__ x,
    const float* __restrict__ wr, const float* __restrict__ wg,
    const float* __restrict__ wb, const float* __restrict__ wc,
    float* __restrict__ out, unsigned int* __restrict__ gmax)
{
    __shared__ float4 F4[L_];          // F4[l] = {f620(wr), f550(wg), f450(wb), f500(wc)}
    __shared__ float Y[2][2][YSZ];     // [iter parity][s within pair][n']  ~4.5 KB

    const int t = threadIdx.x;
    const int b = blockIdx.x & (B_ - 1);
    const int m = blockIdx.x >> 2;

    if (t < 4 * L_) {
        const int c = t / L_, l = t - c * L_;
        const float mus[4] = {620.f, 550.f, 450.f, 500.f};   // component order = {wr,wg,wb,wc} partner
        const float wl = 400.f + 300.f * (float)l / 23.f;    // linspace(400,700,24)
        const float d = (wl - mus[c]) * (1.f / 50.f);
        reinterpret_cast<float*>(&F4[l])[c] = expf(-0.5f * d * d);
    }

    // x row into registers: 6 aligned float4 loads (row = 24 floats = 96 B)
    float xv[L_];
    {
        const float4* x4 = reinterpret_cast<const float4*>(x + ((b * M_ + m) * N_ + t) * L_);
        #pragma unroll
        for (int i = 0; i < L_ / 4; ++i) {
            const float4 v = x4[i];
            xv[4 * i + 0] = v.x; xv[4 * i + 1] = v.y;
            xv[4 * i + 2] = v.z; xv[4 * i + 3] = v.w;
        }
    }

    float Xacc[L_];
    #pragma unroll
    for (int l = 0; l < L_; ++l) Xacc[l] = 0.f;

    const int wbase = (m * N_ + t) * S_;   // thread's weight chunk (22 floats, 8B-aligned)

    #pragma unroll 1
    for (int i = 0; i < S_ / 2; ++i) {     // s = 2i, 2i+1
        float* Y0 = Y[i & 1][0];
        float* Y1 = Y[i & 1][1];

        // zero this iteration's slices (parity-alternated; safe per barrier analysis)
        Y0[t] = 0.f; Y1[t] = 0.f;
        if (t < YSZ - 256) { Y0[256 + t] = 0.f; Y1[256 + t] = 0.f; }

        // normalized weights for s, s+1 (adjacent -> float2 loads)
        const float2 r = *reinterpret_cast<const float2*>(wr + wbase + 2 * i);
        const float2 g = *reinterpret_cast<const float2*>(wg + wbase + 2 * i);
        const float2 u = *reinterpret_cast<const float2*>(wb + wbase + 2 * i);
        const float2 v = *reinterpret_cast<const float2*>(wc + wbase + 2 * i);
        const float i0 = 1.f / (r.x + g.x + u.x + v.x);
        const float i1 = 1.f / (r.y + g.y + u.y + v.y);
        const float a00 = r.x * i0, a10 = g.x * i0, a20 = u.x * i0, a30 = v.x * i0;
        const float a01 = r.y * i1, a11 = g.y * i1, a21 = u.y * i1, a31 = v.y * i1;

        __syncthreads();   // zeros visible; prev phase B fully done

        // Phase A: scatter.  G computed once, kept for phase B.
        float G0[L_], G1[L_];
        #pragma unroll
        for (int l = 0; l < L_; ++l) {
            const float4 f = F4[l];
            G0[l] = a00 * f.x + a10 * f.y + a20 * f.z + a30 * f.w;
            G1[l] = a01 * f.x + a11 * f.y + a21 * f.z + a31 * f.w;
            atomicAdd(&Y0[t + l], G0[l] * xv[l]);
            atomicAdd(&Y1[t + l], G1[l] * xv[l]);
        }

        __syncthreads();   // Y slices complete for s, s+1

        // Phase B: gather into register accumulators.
        #pragma unroll
        for (int l = 0; l < L_; ++l)
            Xacc[l] += G0[l] * Y0[t + l] + G1[l] * Y1[t + l];
    }

    // Epilogue: store unnormalized row + global max.
    float vmax = 0.f;
    #pragma unroll
    for (int l = 0; l < L_; ++l) vmax = fmaxf(vmax, Xacc[l]);

    float4* o4 = reinterpret_cast<float4*>(out + ((b * M_ + m) * N_ + t) * L_);
    #pragma unroll
    for (int i = 0; i < L_ / 4; ++i) {
        float4 vq;
        vq.x = Xacc[4 * i + 0]; vq.y = Xacc[4 * i + 1];
        vq.z = Xacc[4 * i + 2]; vq.w = Xacc[4 * i + 3];
        o4[i] = vq;
    }

    // X >= 0 always (inputs uniform[0,1), bases > 0) so uint compare == float compare.
    #pragma unroll
    for (int off = 32; off > 0; off >>= 1)
        vmax = fmaxf(vmax, __shfl_xor(vmax, off, 64));
    if ((t & 63) == 0) atomicMax(gmax, __float_as_uint(vmax));
}

__global__ __launch_bounds__(256) void cassi_norm(float* __restrict__ out,
                                                  const unsigned int* __restrict__ gmax)
{
    const float inv = 1.f / __uint_as_float(*gmax);
    const int i = (blockIdx.x * 256 + threadIdx.x) * 4;
    float4 v = *reinterpret_cast<float4*>(out + i);
    v.x *= inv; v.y *= inv; v.z *= inv; v.w *= inv;
    *reinterpret_cast<float4*>(out + i) = v;
}

extern "C" void kernel_launch(void* const* d_in, const int* in_sizes, int n_in,
                              void* d_out, int out_size, void* d_ws, size_t ws_size,
                              hipStream_t stream) {
    const float* x  = (const float*)d_in[0];
    const float* wr = (const float*)d_in[1];
    const float* wg = (const float*)d_in[2];
    const float* wb = (const float*)d_in[3];
    const float* wc = (const float*)d_in[4];
    float* out = (float*)d_out;
    unsigned int* gmax = (unsigned int*)d_ws;

    hipMemsetAsync(d_ws, 0, sizeof(unsigned int), stream);  // capture-safe memset node
    cassi_fused<<<B_ * M_, 256, 0, stream>>>(x, wr, wg, wb, wc, out, gmax);
    const int n4blocks = (B_ * M_ * N_ * L_) / 4 / 256;     // 6144, exact
    cassi_norm<<<n4blocks, 256, 0, stream>>>(out, gmax);
}

// Round 5
// 803.420 us; speedup vs baseline: 1.0057x; 1.0057x over previous
//
#include <hip/hip_runtime.h>
#include <math.h>

// Problem constants (reference: B,M,N,L,S,KERN = 4,256,256,24,22,256; KERN==M → tile is identity)
constexpr int B_ = 4, M_ = 256, N_ = 256, L_ = 24, S_ = 22;
constexpr int NY = N_ + L_ - 1;   // 279 dispersion-shifted columns
constexpr int YSZ = 280;          // padded Y slice length (one s)

// R4 post-mortem: dur pinned at ~730us across FOUR structurally different
// kernels (scratch volume, LDS size, fetch pattern all varied wildly; dur
// didn't move 1%). The invariant: 4096 device-scope atomicMax ops to ONE
// d_ws address in the epilogue. Same-address atomics serialize at the
// coherence point (cross-XCD line ping-pong, ~100s of ns each) -> ~730us
// tail that gates kernel retirement. R5: epilogue writes per-BLOCK max to
// d_ws[blockIdx] (plain store), a 1-block reduce kernel makes the scalar.
// Compute phases are byte-identical to R4 (single-variable experiment).
__global__ __launch_bounds__(256) __attribute__((amdgpu_waves_per_eu(3, 3)))
void cassi_fused(
    const float* __restrict__ x,
    const float* __restrict__ wr, const float* __restrict__ wg,
    const float* __restrict__ wb, const float* __restrict__ wc,
    float* __restrict__ out, float* __restrict__ bmax_out)
{
    __shared__ float4 F4[L_];          // F4[l] = {f620(wr), f550(wg), f450(wb), f500(wc)}
    __shared__ float Y[2][2][YSZ];     // [iter parity][s within pair][n']  ~4.5 KB
    __shared__ float wmax[4];

    const int t = threadIdx.x;
    const int b = blockIdx.x & (B_ - 1);
    const int m = blockIdx.x >> 2;

    if (t < 4 * L_) {
        const int c = t / L_, l = t - c * L_;
        const float mus[4] = {620.f, 550.f, 450.f, 500.f};   // component order = {wr,wg,wb,wc} partner
        const float wl = 400.f + 300.f * (float)l / 23.f;    // linspace(400,700,24)
        const float d = (wl - mus[c]) * (1.f / 50.f);
        reinterpret_cast<float*>(&F4[l])[c] = expf(-0.5f * d * d);
    }

    // x row into registers: 6 aligned float4 loads (row = 24 floats = 96 B)
    float xv[L_];
    {
        const float4* x4 = reinterpret_cast<const float4*>(x + ((b * M_ + m) * N_ + t) * L_);
        #pragma unroll
        for (int i = 0; i < L_ / 4; ++i) {
            const float4 v = x4[i];
            xv[4 * i + 0] = v.x; xv[4 * i + 1] = v.y;
            xv[4 * i + 2] = v.z; xv[4 * i + 3] = v.w;
        }
    }

    float Xacc[L_];
    #pragma unroll
    for (int l = 0; l < L_; ++l) Xacc[l] = 0.f;

    const int wbase = (m * N_ + t) * S_;   // thread's weight chunk (22 floats, 8B-aligned)

    #pragma unroll 1
    for (int i = 0; i < S_ / 2; ++i) {     // s = 2i, 2i+1
        float* Y0 = Y[i & 1][0];
        float* Y1 = Y[i & 1][1];

        // zero this iteration's slices (parity-alternated; safe per barrier analysis)
        Y0[t] = 0.f; Y1[t] = 0.f;
        if (t < YSZ - 256) { Y0[256 + t] = 0.f; Y1[256 + t] = 0.f; }

        // normalized weights for s, s+1 (adjacent -> float2 loads)
        const float2 r = *reinterpret_cast<const float2*>(wr + wbase + 2 * i);
        const float2 g = *reinterpret_cast<const float2*>(wg + wbase + 2 * i);
        const float2 u = *reinterpret_cast<const float2*>(wb + wbase + 2 * i);
        const float2 v = *reinterpret_cast<const float2*>(wc + wbase + 2 * i);
        const float i0 = 1.f / (r.x + g.x + u.x + v.x);
        const float i1 = 1.f / (r.y + g.y + u.y + v.y);
        const float a00 = r.x * i0, a10 = g.x * i0, a20 = u.x * i0, a30 = v.x * i0;
        const float a01 = r.y * i1, a11 = g.y * i1, a21 = u.y * i1, a31 = v.y * i1;

        __syncthreads();   // zeros visible; prev phase B fully done

        // Phase A: scatter.  G computed once, kept for phase B.
        float G0[L_], G1[L_];
        #pragma unroll
        for (int l = 0; l < L_; ++l) {
            const float4 f = F4[l];
            G0[l] = a00 * f.x + a10 * f.y + a20 * f.z + a30 * f.w;
            G1[l] = a01 * f.x + a11 * f.y + a21 * f.z + a31 * f.w;
            atomicAdd(&Y0[t + l], G0[l] * xv[l]);
            atomicAdd(&Y1[t + l], G1[l] * xv[l]);
        }

        __syncthreads();   // Y slices complete for s, s+1

        // Phase B: gather into register accumulators.
        #pragma unroll
        for (int l = 0; l < L_; ++l)
            Xacc[l] += G0[l] * Y0[t + l] + G1[l] * Y1[t + l];
    }

    // Epilogue: store unnormalized row + per-block max (NO global atomics).
    float vmax = 0.f;
    #pragma unroll
    for (int l = 0; l < L_; ++l) vmax = fmaxf(vmax, Xacc[l]);

    float4* o4 = reinterpret_cast<float4*>(out + ((b * M_ + m) * N_ + t) * L_);
    #pragma unroll
    for (int i = 0; i < L_ / 4; ++i) {
        float4 vq;
        vq.x = Xacc[4 * i + 0]; vq.y = Xacc[4 * i + 1];
        vq.z = Xacc[4 * i + 2]; vq.w = Xacc[4 * i + 3];
        o4[i] = vq;
    }

    #pragma unroll
    for (int off = 32; off > 0; off >>= 1)
        vmax = fmaxf(vmax, __shfl_xor(vmax, off, 64));
    if ((t & 63) == 0) wmax[t >> 6] = vmax;
    __syncthreads();
    if (t == 0)
        bmax_out[blockIdx.x] = fmaxf(fmaxf(wmax[0], wmax[1]), fmaxf(wmax[2], wmax[3]));
}

// One block: reduce the 1024 per-block maxes to the scalar at gmax.
__global__ __launch_bounds__(256) void cassi_reduce_max(const float* __restrict__ bmax,
                                                        float* __restrict__ gmax)
{
    __shared__ float wm[4];
    const int t = threadIdx.x;
    float v = fmaxf(fmaxf(bmax[t], bmax[t + 256]),
                    fmaxf(bmax[t + 512], bmax[t + 768]));
    #pragma unroll
    for (int off = 32; off > 0; off >>= 1)
        v = fmaxf(v, __shfl_xor(v, off, 64));
    if ((t & 63) == 0) wm[t >> 6] = v;
    __syncthreads();
    if (t == 0) *gmax = fmaxf(fmaxf(wm[0], wm[1]), fmaxf(wm[2], wm[3]));
}

__global__ __launch_bounds__(256) void cassi_norm(float* __restrict__ out,
                                                  const float* __restrict__ gmax)
{
    const float inv = 1.f / *gmax;
    const int i = (blockIdx.x * 256 + threadIdx.x) * 4;
    float4 v = *reinterpret_cast<float4*>(out + i);
    v.x *= inv; v.y *= inv; v.z *= inv; v.w *= inv;
    *reinterpret_cast<float4*>(out + i) = v;
}

extern "C" void kernel_launch(void* const* d_in, const int* in_sizes, int n_in,
                              void* d_out, int out_size, void* d_ws, size_t ws_size,
                              hipStream_t stream) {
    const float* x  = (const float*)d_in[0];
    const float* wr = (const float*)d_in[1];
    const float* wg = (const float*)d_in[2];
    const float* wb = (const float*)d_in[3];
    const float* wc = (const float*)d_in[4];
    float* out  = (float*)d_out;
    float* bmax = (float*)d_ws;          // 1024 per-block maxes
    float* gmax = bmax + 1024;           // final scalar

    cassi_fused<<<B_ * M_, 256, 0, stream>>>(x, wr, wg, wb, wc, out, bmax);
    cassi_reduce_max<<<1, 256, 0, stream>>>(bmax, gmax);
    const int n4blocks = (B_ * M_ * N_ * L_) / 4 / 256;     // 6144, exact
    cassi_norm<<<n4blocks, 256, 0, stream>>>(out, gmax);
}